// Round 12
// baseline (269.010 us; speedup 1.0000x reference)
//
#include <hip/hip_runtime.h>

// ---- problem constants ----
#define BB 2
#define SS 1024
#define HIDDEN 2880
#define NH 64
#define NKV 8
#define HD 64
#define M_TOK 2048          // B*S
#define NQ 4096             // NH*HD
#define NKVD 512            // NKV*HD
#define NQKV 5120           // NQ + 2*NKVD
#define NOUT 2880
#define NOUT_PAD 2944       // 23*128

typedef __attribute__((ext_vector_type(8))) short short8;
typedef __attribute__((ext_vector_type(4))) float f32x4;

__device__ __forceinline__ unsigned short f2b(float x) {
  union { float f; unsigned u; } v; v.f = x;
  unsigned r = (v.u + 0x7FFFu + ((v.u >> 16) & 1u)) >> 16;
  return (unsigned short)r;
}
// truncating f32->bf16 (P-store only: numerator/denominator consistent, bias cancels)
__device__ __forceinline__ unsigned short f2bt(float x) {
  union { float f; unsigned u; } v; v.f = x;
  return (unsigned short)(v.u >> 16);
}

__device__ __forceinline__ void gload16(const void* g, void* l) {
  __builtin_amdgcn_global_load_lds(
      (const __attribute__((address_space(1))) void*)g,
      (__attribute__((address_space(3))) void*)l, 16, 0, 0);
}

// ---- cast x (fp32 -> bf16), vectorized ----
__global__ __launch_bounds__(256) void cast_x_kernel(const float* __restrict__ in,
                                                     unsigned short* __restrict__ out,
                                                     int n4) {
  int idx = blockIdx.x * 256 + threadIdx.x;
  if (idx >= n4) return;
  float4 v = ((const float4*)in)[idx];
  ushort4 o;
  o.x = f2b(v.x); o.y = f2b(v.y); o.z = f2b(v.z); o.w = f2b(v.w);
  ((ushort4*)out)[idx] = o;
}

// ---- transpose + cast (fp32 in): out[n*K + k] = (bf16) in[k*ldin + n] ----
__global__ __launch_bounds__(256) void transpose_cast(const float* __restrict__ in,
                                                      long ldin,
                                                      unsigned short* __restrict__ out,
                                                      int K, int N) {
  __shared__ float t[32][33];
  const int n0 = blockIdx.x * 32, k0 = blockIdx.y * 32;
  const int tx = threadIdx.x, ty = threadIdx.y;
#pragma unroll
  for (int i = 0; i < 4; ++i) {
    int k = k0 + ty + i * 8;
    int n = n0 + tx;
    t[ty + i * 8][tx] = (n < N) ? in[(long)k * ldin + n] : 0.f;
  }
  __syncthreads();
#pragma unroll
  for (int i = 0; i < 4; ++i) {
    int n = n0 + ty + i * 8;
    int k = k0 + tx;
    out[(long)n * K + k] = f2b(t[tx][ty + i * 8]);
  }
}

// ---- RoPE cos/sin table: [2048][32] each ----
__global__ __launch_bounds__(256) void rope_table(const int* __restrict__ pos,
                                                  float* __restrict__ ct,
                                                  float* __restrict__ st) {
  int tid = blockIdx.x * 256 + threadIdx.x;   // < 2048*32
  int t = tid >> 5, i = tid & 31;
  float p = (float)pos[t];
  float f = p * expf(-(float)i * (11.918390573078392f / 32.f));
  ct[tid] = cosf(f);
  st[tid] = sinf(f);
}

// ==== shared GEMM body macro: 128x128 tile, BK=64, 4 waves (2x2), m97 structure ====
// blockIdx.z * Kloop selects the K window (split-K); Kloop==lda for non-split.
#define GEMM128_BODY(Aptr, Bptr, lda, Kloop)                                              \
  __shared__ char lA[128 * 128];                                                          \
  __shared__ char lB[128 * 128];                                                          \
  const int tid = threadIdx.x;                                                            \
  const int lane = tid & 63;                                                              \
  const int w = tid >> 6;                                                                 \
  const int m16 = lane & 15, g4 = lane >> 4;                                              \
  const int wr = w >> 1, wc = w & 1;                                                      \
  const int bm = blockIdx.y * 128, bn = blockIdx.x * 128;                                 \
  const size_t strb = (size_t)(lda) * 2;                                                  \
  const size_t koffb = (size_t)blockIdx.z * (Kloop) * 2;                                  \
  const int srow = tid >> 3;                                                              \
  const int scolb = ((tid & 7) * 16) ^ ((srow & 7) << 4);                                 \
  const int sdst = w * 1024;                                                              \
  const char* ga0 = (const char*)(Aptr) + (size_t)(bm + srow) * strb + koffb + scolb;     \
  const char* gb0 = (const char*)(Bptr) + (size_t)(bn + srow) * strb + koffb + scolb;     \
  const int swz = (m16 & 7) << 4;                                                         \
  const int kc0 = (g4 * 16) ^ swz;                                                        \
  const int kc1 = (64 + g4 * 16) ^ swz;                                                   \
  f32x4 acc[4][4];                                                                        \
  _Pragma("unroll") for (int i = 0; i < 4; ++i)                                           \
  _Pragma("unroll") for (int j = 0; j < 4; ++j) acc[i][j] = (f32x4){0.f, 0.f, 0.f, 0.f};  \
  const int NT = (Kloop) >> 6;                                                            \
  for (int t = 0; t < NT; ++t) {                                                          \
    const size_t ko = (size_t)t * 128;                                                    \
    __syncthreads();                                                                      \
    _Pragma("unroll") for (int i = 0; i < 4; ++i) {                                       \
      gload16(ga0 + (size_t)(i * 32) * strb + ko, lA + i * 4096 + sdst);                  \
      gload16(gb0 + (size_t)(i * 32) * strb + ko, lB + i * 4096 + sdst);                  \
    }                                                                                     \
    __syncthreads();                                                                      \
    short8 af[4][2], bf[4][2];                                                            \
    _Pragma("unroll") for (int mq = 0; mq < 4; ++mq) {                                    \
      const int row = wr * 64 + mq * 16 + m16;                                            \
      af[mq][0] = *(const short8*)(lA + row * 128 + kc0);                                 \
      af[mq][1] = *(const short8*)(lA + row * 128 + kc1);                                 \
    }                                                                                     \
    _Pragma("unroll") for (int nf = 0; nf < 4; ++nf) {                                    \
      const int row = wc * 64 + nf * 16 + m16;                                            \
      bf[nf][0] = *(const short8*)(lB + row * 128 + kc0);                                 \
      bf[nf][1] = *(const short8*)(lB + row * 128 + kc1);                                 \
    }                                                                                     \
    __builtin_amdgcn_s_setprio(1);                                                        \
    _Pragma("unroll") for (int mq = 0; mq < 4; ++mq)                                      \
    _Pragma("unroll") for (int nf = 0; nf < 4; ++nf) {                                    \
      acc[mq][nf] = __builtin_amdgcn_mfma_f32_16x16x32_bf16(af[mq][0], bf[nf][0], acc[mq][nf], 0, 0, 0); \
      acc[mq][nf] = __builtin_amdgcn_mfma_f32_16x16x32_bf16(af[mq][1], bf[nf][1], acc[mq][nf], 0, 0, 0); \
    }                                                                                     \
    __builtin_amdgcn_s_setprio(0);                                                        \
  }

// ---- plain GEMM (fp32 C out) ----
__global__ __launch_bounds__(256, 3) void gemm128(const unsigned short* __restrict__ A,
                                                  const unsigned short* __restrict__ Bt,
                                                  float* __restrict__ C,
                                                  int lda, int ldc, int Nvalid) {
  GEMM128_BODY(A, Bt, lda, lda)
#pragma unroll
  for (int mq = 0; mq < 4; ++mq) {
    const size_t row = bm + wr * 64 + mq * 16 + g4 * 4;
#pragma unroll
    for (int nf = 0; nf < 4; ++nf) {
      const int col = bn + wc * 64 + nf * 16 + m16;
      if (col < Nvalid) {
#pragma unroll
        for (int r = 0; r < 4; ++r)
          C[(row + r) * (size_t)ldc + col] = acc[mq][nf][r];
      }
    }
  }
}

// ---- split-K GEMM (bf16 partial out, grid.z selects partial) ----
__global__ __launch_bounds__(256, 3) void gemm128s(const unsigned short* __restrict__ A,
                                                   const unsigned short* __restrict__ Bt,
                                                   unsigned short* __restrict__ P0,
                                                   unsigned short* __restrict__ P1,
                                                   int lda, int Kloop, int ldc) {
  GEMM128_BODY(A, Bt, lda, Kloop)
  unsigned short* __restrict__ Cw = blockIdx.z ? P1 : P0;
#pragma unroll
  for (int mq = 0; mq < 4; ++mq) {
    const size_t row = bm + wr * 64 + mq * 16 + g4 * 4;
#pragma unroll
    for (int nf = 0; nf < 4; ++nf) {
      const int col = bn + wc * 64 + nf * 16 + m16;
#pragma unroll
      for (int r = 0; r < 4; ++r)
        Cw[(row + r) * (size_t)ldc + col] = f2b(acc[mq][nf][r]);
    }
  }
}

__device__ __forceinline__ float b2f(unsigned short u) {
  union { unsigned u; float f; } v; v.u = ((unsigned)u) << 16; return v.f;
}

// ---- split-K reduce: out[2048][2880] fp32 = p0 + p1 (bf16 [2048][2944]) ----
__global__ __launch_bounds__(256) void reduce_wo2(const unsigned short* __restrict__ p0,
                                                  const unsigned short* __restrict__ p1,
                                                  float* __restrict__ out) {
  int idx = blockIdx.x * 256 + threadIdx.x;   // < 2048*720
  int row = idx / 720, c4 = idx - row * 720;
  const size_t o = (size_t)row * NOUT_PAD + c4 * 4;
  const ushort4 a = *(const ushort4*)(p0 + o);
  const ushort4 b = *(const ushort4*)(p1 + o);
  float4 r;
  r.x = b2f(a.x) + b2f(b.x);
  r.y = b2f(a.y) + b2f(b.y);
  r.z = b2f(a.z) + b2f(b.z);
  r.w = b2f(a.w) + b2f(b.w);
  *(float4*)(out + (size_t)row * 2880 + c4 * 4) = r;
}

// ---- QKV GEMM with fused RoPE + pack epilogue ----
// Q pre-scaled by 0.125*log2(e) so attention softmax runs in exp2 domain.
__global__ __launch_bounds__(256, 3) void gemm128_qkv(const unsigned short* __restrict__ A,
                                                      const unsigned short* __restrict__ Bt,
                                                      const float* __restrict__ ct,
                                                      const float* __restrict__ st,
                                                      unsigned short* __restrict__ qb,
                                                      unsigned short* __restrict__ kb,
                                                      unsigned short* __restrict__ vtb,
                                                      int lda) {
  GEMM128_BODY(A, Bt, lda, lda)
  const int region = (bn < 4096) ? 0 : ((bn < 4608) ? 1 : 2);
#pragma unroll
  for (int mq = 0; mq < 4; ++mq) {
    const int row = bm + wr * 64 + mq * 16 + g4 * 4;   // token index base (+r)
    if (region == 2) {
#pragma unroll
      for (int nf = 0; nf < 4; ++nf) {
        const int d = (bn - 4608) + wc * 64 + nf * 16 + m16;
#pragma unroll
        for (int r = 0; r < 4; ++r) {
          const int t = row + r;
          const int b = t >> 10, sidx = t & 1023;
          vtb[((size_t)(b * NKVD + d)) * SS + sidx] = f2b(acc[mq][nf][r]);
        }
      }
    } else {
#pragma unroll
      for (int nf = 0; nf < 2; ++nf) {
        const int i = nf * 16 + m16;
#pragma unroll
        for (int r = 0; r < 4; ++r) {
          const int t = row + r;
          const int b = t >> 10, sidx = t & 1023;
          const float x1 = acc[mq][nf][r], x2 = acc[mq][nf + 2][r];
          const float c = ct[t * 32 + i], s = st[t * 32 + i];
          if (region == 0) {
            const int h = (bn >> 6) + wc;
            unsigned short* dst = qb + (((size_t)(b * NH + h)) * SS + sidx) * HD;
            dst[i]      = f2b((x1 * c - x2 * s) * 0.18033688011112042f);
            dst[i + 32] = f2b((x1 * s + x2 * c) * 0.18033688011112042f);
          } else {
            const int hk = ((bn - 4096) >> 6) + wc;
            unsigned short* dst = kb + (((size_t)(b * NKV + hk)) * SS + sidx) * HD;
            dst[i]      = f2b(x1 * c - x2 * s);
            dst[i + 32] = f2b(x1 * s + x2 * c);
          }
        }
      }
    }
  }
}

// ---- flash attention (R2-validated structure; softmax in exp2 domain) ----
__global__ __launch_bounds__(512) void attn_fwd(const unsigned short* __restrict__ qb,
                                                const unsigned short* __restrict__ kb,
                                                const unsigned short* __restrict__ vtb,
                                                unsigned short* __restrict__ ao) {
  __shared__ unsigned short kB[2][64 * 64];
  __shared__ unsigned short vB[2][64 * 64];
  __shared__ unsigned short pB[8][32 * 64];
  const int tid = threadIdx.x, lane = tid & 63, w = tid >> 6;
  const int qblk = blockIdx.x;
  const int bh = blockIdx.y;
  const int b = bh >> 6, h = bh & 63, hkv = h >> 3;
  const int m16 = lane & 15, g4 = lane >> 4;
  const int rbase = qblk * 256 + w * 32;

  const unsigned short* qp =
      qb + (((size_t)(b * NH + h)) * SS + rbase + m16) * HD + g4 * 8;
  const short8 q00 = *(const short8*)(qp);
  const short8 q01 = *(const short8*)(qp + 32);
  const short8 q10 = *(const short8*)(qp + 16 * HD);
  const short8 q11 = *(const short8*)(qp + 16 * HD + 32);

  const char* kbp = (const char*)(kb + ((size_t)(b * NKV + hkv)) * SS * HD);
  const char* vbp = (const char*)(vtb + ((size_t)(b * NKV + hkv)) * HD * SS);

  const int lrow = lane >> 3;
  const int lcolb = ((lane & 7) * 16) ^ ((lrow & 7) << 4);
  unsigned short* kDst0 = &kB[0][w * 512];
  unsigned short* kDst1 = &kB[1][w * 512];
  unsigned short* vDst0 = &vB[0][w * 512];
  unsigned short* vDst1 = &vB[1][w * 512];
  const size_t kRowOff = (size_t)(w * 8 + lrow) * 128 + lcolb;
  const size_t vRowOff = (size_t)(w * 8 + lrow) * 2048 + lcolb;

  const short8 ones = {(short)0x3F80, (short)0x3F80, (short)0x3F80, (short)0x3F80,
                       (short)0x3F80, (short)0x3F80, (short)0x3F80, (short)0x3F80};

  f32x4 o0[4], o1[4];
#pragma unroll
  for (int n = 0; n < 4; ++n) { o0[n] = (f32x4){0,0,0,0}; o1[n] = (f32x4){0,0,0,0}; }
  f32x4 lacc0 = (f32x4){0,0,0,0}, lacc1 = (f32x4){0,0,0,0};
  float mrow0[4] = {-1e30f,-1e30f,-1e30f,-1e30f};
  float mrow1[4] = {-1e30f,-1e30f,-1e30f,-1e30f};

  char* pw = (char*)pB[w];
  const int swz_m = (m16 & 7) << 4;
  const int nt = (qblk + 1) * 4;

  gload16(kbp + kRowOff, kDst0);
  gload16(vbp + vRowOff, vDst0);
  __syncthreads();

  for (int t = 0; t < nt; ++t) {
    const int k0 = t * 64;
    const char* kLds = (const char*)kB[t & 1];
    const char* vLds = (const char*)vB[t & 1];
    if (t + 1 < nt) {
      if (t & 1) { gload16(kbp + (size_t)(t + 1) * 8192 + kRowOff, kDst0);
                   gload16(vbp + (size_t)(t + 1) * 128  + vRowOff, vDst0); }
      else       { gload16(kbp + (size_t)(t + 1) * 8192 + kRowOff, kDst1);
                   gload16(vbp + (size_t)(t + 1) * 128  + vRowOff, vDst1); }
    }
    if (k0 < rbase + 32) {
      short8 kf0[4], kf1[4];
#pragma unroll
      for (int kf = 0; kf < 4; ++kf) {
        const int rb = (kf * 16 + m16) * 128;
        kf0[kf] = *(const short8*)(kLds + ((rb + g4 * 16) ^ swz_m));
        kf1[kf] = *(const short8*)(kLds + ((rb + 64 + g4 * 16) ^ swz_m));
      }
      f32x4 s0[4], s1[4];
      __builtin_amdgcn_s_setprio(1);
#pragma unroll
      for (int kf = 0; kf < 4; ++kf) {
        f32x4 z = (f32x4){0,0,0,0};
        z = __builtin_amdgcn_mfma_f32_16x16x32_bf16(q00, kf0[kf], z, 0, 0, 0);
        z = __builtin_amdgcn_mfma_f32_16x16x32_bf16(q01, kf1[kf], z, 0, 0, 0);
        s0[kf] = z;
        f32x4 z2 = (f32x4){0,0,0,0};
        z2 = __builtin_amdgcn_mfma_f32_16x16x32_bf16(q10, kf0[kf], z2, 0, 0, 0);
        z2 = __builtin_amdgcn_mfma_f32_16x16x32_bf16(q11, kf1[kf], z2, 0, 0, 0);
        s1[kf] = z2;
      }
      __builtin_amdgcn_s_setprio(0);
      if (k0 + 63 >= rbase) {
#pragma unroll
        for (int kf = 0; kf < 4; ++kf)
#pragma unroll
          for (int r = 0; r < 4; ++r) {
            const int col = k0 + kf * 16 + m16;
            if (col > rbase + g4 * 4 + r)      s0[kf][r] = -1e30f;
            if (col > rbase + 16 + g4 * 4 + r) s1[kf][r] = -1e30f;
          }
      }
      // defer-max gate (log2 domain: 8 nats ~= 11.5 bits)
      int grow = 0;
#pragma unroll
      for (int kf = 0; kf < 4; ++kf)
#pragma unroll
        for (int r = 0; r < 4; ++r) {
          grow |= (s0[kf][r] > mrow0[r] + 11.5f);
          grow |= (s1[kf][r] > mrow1[r] + 11.5f);
        }
      if (__any(grow)) {
        float mx0[4], mx1[4];
#pragma unroll
        for (int r = 0; r < 4; ++r) {
          mx0[r] = fmaxf(fmaxf(s0[0][r], s0[1][r]), fmaxf(s0[2][r], s0[3][r]));
          mx1[r] = fmaxf(fmaxf(s1[0][r], s1[1][r]), fmaxf(s1[2][r], s1[3][r]));
        }
#pragma unroll
        for (int off = 1; off <= 8; off <<= 1)
#pragma unroll
          for (int r = 0; r < 4; ++r) {
            mx0[r] = fmaxf(mx0[r], __shfl_xor(mx0[r], off));
            mx1[r] = fmaxf(mx1[r], __shfl_xor(mx1[r], off));
          }
#pragma unroll
        for (int r = 0; r < 4; ++r) {
          float mn0 = fmaxf(mrow0[r], mx0[r]);
          float sc0 = exp2f(mrow0[r] - mn0);
          mrow0[r] = mn0; lacc0[r] *= sc0;
          float mn1 = fmaxf(mrow1[r], mx1[r]);
          float sc1 = exp2f(mrow1[r] - mn1);
          mrow1[r] = mn1; lacc1[r] *= sc1;
#pragma unroll
          for (int n = 0; n < 4; ++n) { o0[n][r] *= sc0; o1[n][r] *= sc1; }
        }
      }
#pragma unroll
      for (int kf = 0; kf < 4; ++kf)
#pragma unroll
        for (int r = 0; r < 4; ++r) {
          const int colb = (kf * 16 + m16) * 2;
          int row = g4 * 4 + r;
          *(unsigned short*)(pw + ((row * 128 + colb) ^ ((row & 7) << 4))) =
              f2bt(exp2f(s0[kf][r] - mrow0[r]));
          row += 16;
          *(unsigned short*)(pw + ((row * 128 + colb) ^ ((row & 7) << 4))) =
              f2bt(exp2f(s1[kf][r] - mrow1[r]));
        }
      const int prb0 = m16 * 128, prb1 = (16 + m16) * 128;
      short8 pf00 = *(const short8*)(pw + ((prb0 + g4 * 16) ^ swz_m));
      short8 pf01 = *(const short8*)(pw + ((prb0 + 64 + g4 * 16) ^ swz_m));
      short8 pf10 = *(const short8*)(pw + ((prb1 + g4 * 16) ^ swz_m));
      short8 pf11 = *(const short8*)(pw + ((prb1 + 64 + g4 * 16) ^ swz_m));
      __builtin_amdgcn_s_setprio(1);
      lacc0 = __builtin_amdgcn_mfma_f32_16x16x32_bf16(pf00, ones, lacc0, 0, 0, 0);
      lacc0 = __builtin_amdgcn_mfma_f32_16x16x32_bf16(pf01, ones, lacc0, 0, 0, 0);
      lacc1 = __builtin_amdgcn_mfma_f32_16x16x32_bf16(pf10, ones, lacc1, 0, 0, 0);
      lacc1 = __builtin_amdgcn_mfma_f32_16x16x32_bf16(pf11, ones, lacc1, 0, 0, 0);
#pragma unroll
      for (int n = 0; n < 4; ++n) {
        const int rb = (n * 16 + m16) * 128;
        short8 vf0 = *(const short8*)(vLds + ((rb + g4 * 16) ^ swz_m));
        short8 vf1 = *(const short8*)(vLds + ((rb + 64 + g4 * 16) ^ swz_m));
        o0[n] = __builtin_amdgcn_mfma_f32_16x16x32_bf16(pf00, vf0, o0[n], 0, 0, 0);
        o0[n] = __builtin_amdgcn_mfma_f32_16x16x32_bf16(pf01, vf1, o0[n], 0, 0, 0);
        o1[n] = __builtin_amdgcn_mfma_f32_16x16x32_bf16(pf10, vf0, o1[n], 0, 0, 0);
        o1[n] = __builtin_amdgcn_mfma_f32_16x16x32_bf16(pf11, vf1, o1[n], 0, 0, 0);
      }
      __builtin_amdgcn_s_setprio(0);
    }
    __syncthreads();
  }

  float inv0[4], inv1[4];
#pragma unroll
  for (int r = 0; r < 4; ++r) { inv0[r] = 1.f / lacc0[r]; inv1[r] = 1.f / lacc1[r]; }
  const size_t row0 = (size_t)b * SS + rbase + g4 * 4;
#pragma unroll
  for (int n = 0; n < 4; ++n)
#pragma unroll
    for (int r = 0; r < 4; ++r) {
      ao[(row0 + r) * (size_t)NQ + h * 64 + n * 16 + m16] = f2b(o0[n][r] * inv0[r]);
      ao[(row0 + 16 + r) * (size_t)NQ + h * 64 + n * 16 + m16] = f2b(o1[n][r] * inv1[r]);
    }
}

// ---- workspace layout (bytes), total 103,677,952 ----
// xb+wqkvt region (0..41,287,680) is dead after QKV gemm -> reused for wo partials.
constexpr size_t OFF_XB    = 0;                          // 11,796,480
constexpr size_t OFF_WQKVT = 11796480;                   // 29,491,200
constexpr size_t OFF_WP0   = 0;                          // 2048*2944*2 = 12,058,624
constexpr size_t OFF_WP1   = 12058624;                   // 12,058,624 (ends 24,117,248)
constexpr size_t OFF_WOT   = 41287680;                   // 24,117,248
constexpr size_t OFF_COS   = 65404928;                   // 262,144
constexpr size_t OFF_SIN   = 65667072;                   // 262,144
constexpr size_t OFF_QB    = 65929216;                   // 16,777,216
constexpr size_t OFF_KB    = 82706432;                   // 2,097,152
constexpr size_t OFF_VTB   = 84803584;                   // 2,097,152
constexpr size_t OFF_ATTNB = 86900736;                   // 16,777,216

extern "C" void kernel_launch(void* const* d_in, const int* in_sizes, int n_in,
                              void* d_out, int out_size, void* d_ws, size_t ws_size,
                              hipStream_t stream) {
  const float* x  = (const float*)d_in[0];
  const float* wq = (const float*)d_in[1];
  const float* wk = (const float*)d_in[2];
  const float* wv = (const float*)d_in[3];
  const float* wo = (const float*)d_in[4];
  const int* pos  = (const int*)d_in[5];
  float* out = (float*)d_out;
  char* ws = (char*)d_ws;

  unsigned short* xb    = (unsigned short*)(ws + OFF_XB);
  unsigned short* wqkvt = (unsigned short*)(ws + OFF_WQKVT);
  unsigned short* wp0   = (unsigned short*)(ws + OFF_WP0);
  unsigned short* wp1   = (unsigned short*)(ws + OFF_WP1);
  unsigned short* wot   = (unsigned short*)(ws + OFF_WOT);
  float* ct             = (float*)(ws + OFF_COS);
  float* st             = (float*)(ws + OFF_SIN);
  unsigned short* qbuf  = (unsigned short*)(ws + OFF_QB);
  unsigned short* kbuf  = (unsigned short*)(ws + OFF_KB);
  unsigned short* vtb   = (unsigned short*)(ws + OFF_VTB);
  unsigned short* attnb = (unsigned short*)(ws + OFF_ATTNB);

  cast_x_kernel<<<(M_TOK * HIDDEN / 4 + 255) / 256, 256, 0, stream>>>(x, xb, M_TOK * HIDDEN / 4);
  rope_table<<<(M_TOK * 32) / 256, 256, 0, stream>>>(pos, ct, st);
  transpose_cast<<<dim3(NQ / 32, HIDDEN / 32), dim3(32, 8), 0, stream>>>(
      wq, NQ, wqkvt, HIDDEN, NQ);
  transpose_cast<<<dim3(NKVD / 32, HIDDEN / 32), dim3(32, 8), 0, stream>>>(
      wk, NKVD, wqkvt + (size_t)NQ * HIDDEN, HIDDEN, NKVD);
  transpose_cast<<<dim3(NKVD / 32, HIDDEN / 32), dim3(32, 8), 0, stream>>>(
      wv, NKVD, wqkvt + (size_t)(NQ + NKVD) * HIDDEN, HIDDEN, NKVD);
  transpose_cast<<<dim3(NOUT_PAD / 32, NQ / 32), dim3(32, 8), 0, stream>>>(
      wo, NOUT, wot, NQ, NOUT);
  // QKV projection with fused RoPE+pack epilogue: grid 40x16 = 640 blocks
  gemm128_qkv<<<dim3(NQKV / 128, M_TOK / 128), 256, 0, stream>>>(
      xb, wqkvt, ct, st, qbuf, kbuf, vtb, HIDDEN);
  // attention
  attn_fwd<<<dim3(4, BB * NH), 512, 0, stream>>>(qbuf, kbuf, vtb, attnb);
  // output projection: split-K=2 (K=2x2048), grid 23x16x2 = 736 blocks, bf16 partials
  gemm128s<<<dim3(NOUT_PAD / 128, M_TOK / 128, 2), 256, 0, stream>>>(
      attnb, wot, wp0, wp1, NQ, NQ / 2, NOUT_PAD);
  reduce_wo2<<<(M_TOK * 720) / 256, 256, 0, stream>>>(wp0, wp1, out);
}

// Round 13
// 255.162 us; speedup vs baseline: 1.0543x; 1.0543x over previous
//
#include <hip/hip_runtime.h>

// ---- problem constants ----
#define BB 2
#define SS 1024
#define HIDDEN 2880
#define NH 64
#define NKV 8
#define HD 64
#define M_TOK 2048          // B*S
#define NQ 4096             // NH*HD
#define NKVD 512            // NKV*HD
#define NQKV 5120           // NQ + 2*NKVD
#define NOUT 2880
#define NOUT_PAD 2944       // 23*128

typedef __attribute__((ext_vector_type(8))) short short8;
typedef __attribute__((ext_vector_type(4))) float f32x4;

__device__ __forceinline__ unsigned short f2b(float x) {
  union { float f; unsigned u; } v; v.f = x;
  unsigned r = (v.u + 0x7FFFu + ((v.u >> 16) & 1u)) >> 16;
  return (unsigned short)r;
}

__device__ __forceinline__ void gload16(const void* g, void* l) {
  __builtin_amdgcn_global_load_lds(
      (const __attribute__((address_space(1))) void*)g,
      (__attribute__((address_space(3))) void*)l, 16, 0, 0);
}

// ---- cast x (fp32 -> bf16), vectorized ----
__global__ __launch_bounds__(256) void cast_x_kernel(const float* __restrict__ in,
                                                     unsigned short* __restrict__ out,
                                                     int n4) {
  int idx = blockIdx.x * 256 + threadIdx.x;
  if (idx >= n4) return;
  float4 v = ((const float4*)in)[idx];
  ushort4 o;
  o.x = f2b(v.x); o.y = f2b(v.y); o.z = f2b(v.z); o.w = f2b(v.w);
  ((ushort4*)out)[idx] = o;
}

// ---- transpose + cast (fp32 in): out[n*K + k] = (bf16) in[k*ldin + n] ----
__global__ __launch_bounds__(256) void transpose_cast(const float* __restrict__ in,
                                                      long ldin,
                                                      unsigned short* __restrict__ out,
                                                      int K, int N) {
  __shared__ float t[32][33];
  const int n0 = blockIdx.x * 32, k0 = blockIdx.y * 32;
  const int tx = threadIdx.x, ty = threadIdx.y;
#pragma unroll
  for (int i = 0; i < 4; ++i) {
    int k = k0 + ty + i * 8;
    int n = n0 + tx;
    t[ty + i * 8][tx] = (n < N) ? in[(long)k * ldin + n] : 0.f;
  }
  __syncthreads();
#pragma unroll
  for (int i = 0; i < 4; ++i) {
    int n = n0 + ty + i * 8;
    int k = k0 + tx;
    out[(long)n * K + k] = f2b(t[tx][ty + i * 8]);
  }
}

// ---- RoPE cos/sin table: [2048][32] each ----
__global__ __launch_bounds__(256) void rope_table(const int* __restrict__ pos,
                                                  float* __restrict__ ct,
                                                  float* __restrict__ st) {
  int tid = blockIdx.x * 256 + threadIdx.x;   // < 2048*32
  int t = tid >> 5, i = tid & 31;
  float p = (float)pos[t];
  float f = p * expf(-(float)i * (11.918390573078392f / 32.f));
  ct[tid] = cosf(f);
  st[tid] = sinf(f);
}

// ==== shared GEMM body macro: 128x128 tile, BK=64, 4 waves (2x2), m97 structure ====
// NXT = grid x-tiles (compile-time); includes bijective XCD swizzle (T1, m204):
// hw id -> XCD = hw%8 gets contiguous logical run of nwg/8 blocks -> A-panel L2 reuse.
// Requires nwg % 8 == 0 (both uses: 640, 368).
#define GEMM128_BODY(Aptr, Bptr, lda, NXT)                                                \
  __shared__ char lA[128 * 128];                                                          \
  __shared__ char lB[128 * 128];                                                          \
  const int tid = threadIdx.x;                                                            \
  const int lane = tid & 63;                                                              \
  const int w = tid >> 6;                                                                 \
  const int m16 = lane & 15, g4 = lane >> 4;                                              \
  const int wr = w >> 1, wc = w & 1;                                                      \
  const int _nwg = (NXT) * gridDim.y;                                                     \
  const int _hw = blockIdx.y * (NXT) + blockIdx.x;                                        \
  const int _lg = (_hw & 7) * (_nwg >> 3) + (_hw >> 3);                                   \
  const int bm = (_lg / (NXT)) * 128, bn = (_lg % (NXT)) * 128;                           \
  const size_t strb = (size_t)(lda) * 2;                                                  \
  const int srow = tid >> 3;                                                              \
  const int scolb = ((tid & 7) * 16) ^ ((srow & 7) << 4);                                 \
  const int sdst = w * 1024;                                                              \
  const char* ga0 = (const char*)(Aptr) + (size_t)(bm + srow) * strb + scolb;             \
  const char* gb0 = (const char*)(Bptr) + (size_t)(bn + srow) * strb + scolb;             \
  const int swz = (m16 & 7) << 4;                                                         \
  const int kc0 = (g4 * 16) ^ swz;                                                        \
  const int kc1 = (64 + g4 * 16) ^ swz;                                                   \
  f32x4 acc[4][4];                                                                        \
  _Pragma("unroll") for (int i = 0; i < 4; ++i)                                           \
  _Pragma("unroll") for (int j = 0; j < 4; ++j) acc[i][j] = (f32x4){0.f, 0.f, 0.f, 0.f};  \
  const int NT = (lda) >> 6;                                                              \
  for (int t = 0; t < NT; ++t) {                                                          \
    const size_t ko = (size_t)t * 128;                                                    \
    __syncthreads();                                                                      \
    _Pragma("unroll") for (int i = 0; i < 4; ++i) {                                       \
      gload16(ga0 + (size_t)(i * 32) * strb + ko, lA + i * 4096 + sdst);                  \
      gload16(gb0 + (size_t)(i * 32) * strb + ko, lB + i * 4096 + sdst);                  \
    }                                                                                     \
    __syncthreads();                                                                      \
    short8 af[4][2], bf[4][2];                                                            \
    _Pragma("unroll") for (int mq = 0; mq < 4; ++mq) {                                    \
      const int row = wr * 64 + mq * 16 + m16;                                            \
      af[mq][0] = *(const short8*)(lA + row * 128 + kc0);                                 \
      af[mq][1] = *(const short8*)(lA + row * 128 + kc1);                                 \
    }                                                                                     \
    _Pragma("unroll") for (int nf = 0; nf < 4; ++nf) {                                    \
      const int row = wc * 64 + nf * 16 + m16;                                            \
      bf[nf][0] = *(const short8*)(lB + row * 128 + kc0);                                 \
      bf[nf][1] = *(const short8*)(lB + row * 128 + kc1);                                 \
    }                                                                                     \
    __builtin_amdgcn_s_setprio(1);                                                        \
    _Pragma("unroll") for (int mq = 0; mq < 4; ++mq)                                      \
    _Pragma("unroll") for (int nf = 0; nf < 4; ++nf) {                                    \
      acc[mq][nf] = __builtin_amdgcn_mfma_f32_16x16x32_bf16(af[mq][0], bf[nf][0], acc[mq][nf], 0, 0, 0); \
      acc[mq][nf] = __builtin_amdgcn_mfma_f32_16x16x32_bf16(af[mq][1], bf[nf][1], acc[mq][nf], 0, 0, 0); \
    }                                                                                     \
    __builtin_amdgcn_s_setprio(0);                                                        \
  }

// ---- plain GEMM (fp32 C out) -- wo projection (grid x = 23) ----
__global__ __launch_bounds__(256, 3) void gemm128(const unsigned short* __restrict__ A,
                                                  const unsigned short* __restrict__ Bt,
                                                  float* __restrict__ C,
                                                  int lda, int ldc, int Nvalid) {
  GEMM128_BODY(A, Bt, lda, 23)
#pragma unroll
  for (int mq = 0; mq < 4; ++mq) {
    const size_t row = bm + wr * 64 + mq * 16 + g4 * 4;
#pragma unroll
    for (int nf = 0; nf < 4; ++nf) {
      const int col = bn + wc * 64 + nf * 16 + m16;
      if (col < Nvalid) {
#pragma unroll
        for (int r = 0; r < 4; ++r)
          C[(row + r) * (size_t)ldc + col] = acc[mq][nf][r];
      }
    }
  }
}

// ---- QKV GEMM with fused RoPE + pack epilogue (grid x = 40) ----
__global__ __launch_bounds__(256, 3) void gemm128_qkv(const unsigned short* __restrict__ A,
                                                      const unsigned short* __restrict__ Bt,
                                                      const float* __restrict__ ct,
                                                      const float* __restrict__ st,
                                                      unsigned short* __restrict__ qb,
                                                      unsigned short* __restrict__ kb,
                                                      unsigned short* __restrict__ vtb,
                                                      int lda) {
  GEMM128_BODY(A, Bt, lda, 40)
  const int region = (bn < 4096) ? 0 : ((bn < 4608) ? 1 : 2);
#pragma unroll
  for (int mq = 0; mq < 4; ++mq) {
    const int row = bm + wr * 64 + mq * 16 + g4 * 4;   // token index base (+r)
    if (region == 2) {
#pragma unroll
      for (int nf = 0; nf < 4; ++nf) {
        const int d = (bn - 4608) + wc * 64 + nf * 16 + m16;
#pragma unroll
        for (int r = 0; r < 4; ++r) {
          const int t = row + r;
          const int b = t >> 10, sidx = t & 1023;
          vtb[((size_t)(b * NKVD + d)) * SS + sidx] = f2b(acc[mq][nf][r]);
        }
      }
    } else {
#pragma unroll
      for (int nf = 0; nf < 2; ++nf) {
        const int i = nf * 16 + m16;
#pragma unroll
        for (int r = 0; r < 4; ++r) {
          const int t = row + r;
          const int b = t >> 10, sidx = t & 1023;
          const float x1 = acc[mq][nf][r], x2 = acc[mq][nf + 2][r];
          const float c = ct[t * 32 + i], s = st[t * 32 + i];
          if (region == 0) {
            const int h = (bn >> 6) + wc;
            unsigned short* dst = qb + (((size_t)(b * NH + h)) * SS + sidx) * HD;
            dst[i]      = f2b((x1 * c - x2 * s) * 0.125f);
            dst[i + 32] = f2b((x1 * s + x2 * c) * 0.125f);
          } else {
            const int hk = ((bn - 4096) >> 6) + wc;
            unsigned short* dst = kb + (((size_t)(b * NKV + hk)) * SS + sidx) * HD;
            dst[i]      = f2b(x1 * c - x2 * s);
            dst[i + 32] = f2b(x1 * s + x2 * c);
          }
        }
      }
    }
  }
}

// ---- flash attention (R10-validated version, byte-identical) ----
__global__ __launch_bounds__(512) void attn_fwd(const unsigned short* __restrict__ qb,
                                                const unsigned short* __restrict__ kb,
                                                const unsigned short* __restrict__ vtb,
                                                unsigned short* __restrict__ ao) {
  __shared__ unsigned short kB[2][64 * 64];
  __shared__ unsigned short vB[2][64 * 64];
  __shared__ unsigned short pB[8][32 * 64];
  const int tid = threadIdx.x, lane = tid & 63, w = tid >> 6;
  const int qblk = blockIdx.x;
  const int bh = blockIdx.y;
  const int b = bh >> 6, h = bh & 63, hkv = h >> 3;
  const int m16 = lane & 15, g4 = lane >> 4;
  const int rbase = qblk * 256 + w * 32;

  const unsigned short* qp =
      qb + (((size_t)(b * NH + h)) * SS + rbase + m16) * HD + g4 * 8;
  const short8 q00 = *(const short8*)(qp);
  const short8 q01 = *(const short8*)(qp + 32);
  const short8 q10 = *(const short8*)(qp + 16 * HD);
  const short8 q11 = *(const short8*)(qp + 16 * HD + 32);

  const char* kbp = (const char*)(kb + ((size_t)(b * NKV + hkv)) * SS * HD);
  const char* vbp = (const char*)(vtb + ((size_t)(b * NKV + hkv)) * HD * SS);

  const int lrow = lane >> 3;
  const int lcolb = ((lane & 7) * 16) ^ ((lrow & 7) << 4);
  unsigned short* kDst0 = &kB[0][w * 512];
  unsigned short* kDst1 = &kB[1][w * 512];
  unsigned short* vDst0 = &vB[0][w * 512];
  unsigned short* vDst1 = &vB[1][w * 512];
  const size_t kRowOff = (size_t)(w * 8 + lrow) * 128 + lcolb;
  const size_t vRowOff = (size_t)(w * 8 + lrow) * 2048 + lcolb;

  const short8 ones = {(short)0x3F80, (short)0x3F80, (short)0x3F80, (short)0x3F80,
                       (short)0x3F80, (short)0x3F80, (short)0x3F80, (short)0x3F80};

  f32x4 o0[4], o1[4];
#pragma unroll
  for (int n = 0; n < 4; ++n) { o0[n] = (f32x4){0,0,0,0}; o1[n] = (f32x4){0,0,0,0}; }
  f32x4 lacc0 = (f32x4){0,0,0,0}, lacc1 = (f32x4){0,0,0,0};
  float mrow0[4] = {-1e30f,-1e30f,-1e30f,-1e30f};
  float mrow1[4] = {-1e30f,-1e30f,-1e30f,-1e30f};

  char* pw = (char*)pB[w];
  const int swz_m = (m16 & 7) << 4;
  const int nt = (qblk + 1) * 4;

  gload16(kbp + kRowOff, kDst0);
  gload16(vbp + vRowOff, vDst0);
  __syncthreads();

  for (int t = 0; t < nt; ++t) {
    const int k0 = t * 64;
    const char* kLds = (const char*)kB[t & 1];
    const char* vLds = (const char*)vB[t & 1];
    if (t + 1 < nt) {
      if (t & 1) { gload16(kbp + (size_t)(t + 1) * 8192 + kRowOff, kDst0);
                   gload16(vbp + (size_t)(t + 1) * 128  + vRowOff, vDst0); }
      else       { gload16(kbp + (size_t)(t + 1) * 8192 + kRowOff, kDst1);
                   gload16(vbp + (size_t)(t + 1) * 128  + vRowOff, vDst1); }
    }
    if (k0 < rbase + 32) {
      short8 kf0[4], kf1[4];
#pragma unroll
      for (int kf = 0; kf < 4; ++kf) {
        const int rb = (kf * 16 + m16) * 128;
        kf0[kf] = *(const short8*)(kLds + ((rb + g4 * 16) ^ swz_m));
        kf1[kf] = *(const short8*)(kLds + ((rb + 64 + g4 * 16) ^ swz_m));
      }
      f32x4 s0[4], s1[4];
      __builtin_amdgcn_s_setprio(1);
#pragma unroll
      for (int kf = 0; kf < 4; ++kf) {
        f32x4 z = (f32x4){0,0,0,0};
        z = __builtin_amdgcn_mfma_f32_16x16x32_bf16(q00, kf0[kf], z, 0, 0, 0);
        z = __builtin_amdgcn_mfma_f32_16x16x32_bf16(q01, kf1[kf], z, 0, 0, 0);
        s0[kf] = z;
        f32x4 z2 = (f32x4){0,0,0,0};
        z2 = __builtin_amdgcn_mfma_f32_16x16x32_bf16(q10, kf0[kf], z2, 0, 0, 0);
        z2 = __builtin_amdgcn_mfma_f32_16x16x32_bf16(q11, kf1[kf], z2, 0, 0, 0);
        s1[kf] = z2;
      }
      __builtin_amdgcn_s_setprio(0);
      if (k0 + 63 >= rbase) {
#pragma unroll
        for (int kf = 0; kf < 4; ++kf)
#pragma unroll
          for (int r = 0; r < 4; ++r) {
            const int col = k0 + kf * 16 + m16;
            if (col > rbase + g4 * 4 + r)      s0[kf][r] = -1e30f;
            if (col > rbase + 16 + g4 * 4 + r) s1[kf][r] = -1e30f;
          }
      }
      int grow = 0;
#pragma unroll
      for (int kf = 0; kf < 4; ++kf)
#pragma unroll
        for (int r = 0; r < 4; ++r) {
          grow |= (s0[kf][r] > mrow0[r] + 8.f);
          grow |= (s1[kf][r] > mrow1[r] + 8.f);
        }
      if (__any(grow)) {
        float mx0[4], mx1[4];
#pragma unroll
        for (int r = 0; r < 4; ++r) {
          mx0[r] = fmaxf(fmaxf(s0[0][r], s0[1][r]), fmaxf(s0[2][r], s0[3][r]));
          mx1[r] = fmaxf(fmaxf(s1[0][r], s1[1][r]), fmaxf(s1[2][r], s1[3][r]));
        }
#pragma unroll
        for (int off = 1; off <= 8; off <<= 1)
#pragma unroll
          for (int r = 0; r < 4; ++r) {
            mx0[r] = fmaxf(mx0[r], __shfl_xor(mx0[r], off));
            mx1[r] = fmaxf(mx1[r], __shfl_xor(mx1[r], off));
          }
#pragma unroll
        for (int r = 0; r < 4; ++r) {
          float mn0 = fmaxf(mrow0[r], mx0[r]);
          float sc0 = __expf(mrow0[r] - mn0);
          mrow0[r] = mn0; lacc0[r] *= sc0;
          float mn1 = fmaxf(mrow1[r], mx1[r]);
          float sc1 = __expf(mrow1[r] - mn1);
          mrow1[r] = mn1; lacc1[r] *= sc1;
#pragma unroll
          for (int n = 0; n < 4; ++n) { o0[n][r] *= sc0; o1[n][r] *= sc1; }
        }
      }
#pragma unroll
      for (int kf = 0; kf < 4; ++kf)
#pragma unroll
        for (int r = 0; r < 4; ++r) {
          const int colb = (kf * 16 + m16) * 2;
          int row = g4 * 4 + r;
          *(unsigned short*)(pw + ((row * 128 + colb) ^ ((row & 7) << 4))) =
              f2b(__expf(s0[kf][r] - mrow0[r]));
          row += 16;
          *(unsigned short*)(pw + ((row * 128 + colb) ^ ((row & 7) << 4))) =
              f2b(__expf(s1[kf][r] - mrow1[r]));
        }
      const int prb0 = m16 * 128, prb1 = (16 + m16) * 128;
      short8 pf00 = *(const short8*)(pw + ((prb0 + g4 * 16) ^ swz_m));
      short8 pf01 = *(const short8*)(pw + ((prb0 + 64 + g4 * 16) ^ swz_m));
      short8 pf10 = *(const short8*)(pw + ((prb1 + g4 * 16) ^ swz_m));
      short8 pf11 = *(const short8*)(pw + ((prb1 + 64 + g4 * 16) ^ swz_m));
      __builtin_amdgcn_s_setprio(1);
      lacc0 = __builtin_amdgcn_mfma_f32_16x16x32_bf16(pf00, ones, lacc0, 0, 0, 0);
      lacc0 = __builtin_amdgcn_mfma_f32_16x16x32_bf16(pf01, ones, lacc0, 0, 0, 0);
      lacc1 = __builtin_amdgcn_mfma_f32_16x16x32_bf16(pf10, ones, lacc1, 0, 0, 0);
      lacc1 = __builtin_amdgcn_mfma_f32_16x16x32_bf16(pf11, ones, lacc1, 0, 0, 0);
#pragma unroll
      for (int n = 0; n < 4; ++n) {
        const int rb = (n * 16 + m16) * 128;
        short8 vf0 = *(const short8*)(vLds + ((rb + g4 * 16) ^ swz_m));
        short8 vf1 = *(const short8*)(vLds + ((rb + 64 + g4 * 16) ^ swz_m));
        o0[n] = __builtin_amdgcn_mfma_f32_16x16x32_bf16(pf00, vf0, o0[n], 0, 0, 0);
        o0[n] = __builtin_amdgcn_mfma_f32_16x16x32_bf16(pf01, vf1, o0[n], 0, 0, 0);
        o1[n] = __builtin_amdgcn_mfma_f32_16x16x32_bf16(pf10, vf0, o1[n], 0, 0, 0);
        o1[n] = __builtin_amdgcn_mfma_f32_16x16x32_bf16(pf11, vf1, o1[n], 0, 0, 0);
      }
      __builtin_amdgcn_s_setprio(0);
    }
    __syncthreads();
  }

  float inv0[4], inv1[4];
#pragma unroll
  for (int r = 0; r < 4; ++r) { inv0[r] = 1.f / lacc0[r]; inv1[r] = 1.f / lacc1[r]; }
  const size_t row0 = (size_t)b * SS + rbase + g4 * 4;
#pragma unroll
  for (int n = 0; n < 4; ++n)
#pragma unroll
    for (int r = 0; r < 4; ++r) {
      ao[(row0 + r) * (size_t)NQ + h * 64 + n * 16 + m16] = f2b(o0[n][r] * inv0[r]);
      ao[(row0 + 16 + r) * (size_t)NQ + h * 64 + n * 16 + m16] = f2b(o1[n][r] * inv1[r]);
    }
}

// ---- workspace layout (bytes), total 103,677,952 ----
constexpr size_t OFF_XB    = 0;                          // 11,796,480
constexpr size_t OFF_WQKVT = 11796480;                   // 29,491,200
constexpr size_t OFF_WOT   = 41287680;                   // 24,117,248
constexpr size_t OFF_COS   = 65404928;                   // 262,144
constexpr size_t OFF_SIN   = 65667072;                   // 262,144
constexpr size_t OFF_QB    = 65929216;                   // 16,777,216
constexpr size_t OFF_KB    = 82706432;                   // 2,097,152
constexpr size_t OFF_VTB   = 84803584;                   // 2,097,152
constexpr size_t OFF_ATTNB = 86900736;                   // 16,777,216

extern "C" void kernel_launch(void* const* d_in, const int* in_sizes, int n_in,
                              void* d_out, int out_size, void* d_ws, size_t ws_size,
                              hipStream_t stream) {
  const float* x  = (const float*)d_in[0];
  const float* wq = (const float*)d_in[1];
  const float* wk = (const float*)d_in[2];
  const float* wv = (const float*)d_in[3];
  const float* wo = (const float*)d_in[4];
  const int* pos  = (const int*)d_in[5];
  float* out = (float*)d_out;
  char* ws = (char*)d_ws;

  unsigned short* xb    = (unsigned short*)(ws + OFF_XB);
  unsigned short* wqkvt = (unsigned short*)(ws + OFF_WQKVT);
  unsigned short* wot   = (unsigned short*)(ws + OFF_WOT);
  float* ct             = (float*)(ws + OFF_COS);
  float* st             = (float*)(ws + OFF_SIN);
  unsigned short* qbuf  = (unsigned short*)(ws + OFF_QB);
  unsigned short* kbuf  = (unsigned short*)(ws + OFF_KB);
  unsigned short* vtb   = (unsigned short*)(ws + OFF_VTB);
  unsigned short* attnb = (unsigned short*)(ws + OFF_ATTNB);

  cast_x_kernel<<<(M_TOK * HIDDEN / 4 + 255) / 256, 256, 0, stream>>>(x, xb, M_TOK * HIDDEN / 4);
  rope_table<<<(M_TOK * 32) / 256, 256, 0, stream>>>(pos, ct, st);
  transpose_cast<<<dim3(NQ / 32, HIDDEN / 32), dim3(32, 8), 0, stream>>>(
      wq, NQ, wqkvt, HIDDEN, NQ);
  transpose_cast<<<dim3(NKVD / 32, HIDDEN / 32), dim3(32, 8), 0, stream>>>(
      wk, NKVD, wqkvt + (size_t)NQ * HIDDEN, HIDDEN, NKVD);
  transpose_cast<<<dim3(NKVD / 32, HIDDEN / 32), dim3(32, 8), 0, stream>>>(
      wv, NKVD, wqkvt + (size_t)(NQ + NKVD) * HIDDEN, HIDDEN, NKVD);
  transpose_cast<<<dim3(NOUT_PAD / 32, NQ / 32), dim3(32, 8), 0, stream>>>(
      wo, NOUT, wot, NQ, NOUT);
  // QKV projection with fused RoPE+pack epilogue: grid 40x16 = 640 blocks (XCD-swizzled)
  gemm128_qkv<<<dim3(NQKV / 128, M_TOK / 128), 256, 0, stream>>>(
      xb, wqkvt, ct, st, qbuf, kbuf, vtb, HIDDEN);
  // attention
  attn_fwd<<<dim3(4, BB * NH), 512, 0, stream>>>(qbuf, kbuf, vtb, attnb);
  // output projection: grid 23x16 = 368 blocks (XCD-swizzled), fp32 direct to d_out
  gemm128<<<dim3(NOUT_PAD / 128, M_TOK / 128), 256, 0, stream>>>(
      attnb, wot, out, NQ, NOUT, NOUT);
}

// Round 14
// 232.546 us; speedup vs baseline: 1.1568x; 1.0973x over previous
//
#include <hip/hip_runtime.h>

// ---- problem constants ----
#define BB 2
#define SS 1024
#define HIDDEN 2880
#define NH 64
#define NKV 8
#define HD 64
#define M_TOK 2048          // B*S
#define NQ 4096             // NH*HD
#define NKVD 512            // NKV*HD
#define NQKV 5120           // NQ + 2*NKVD
#define NOUT 2880
#define NOUT_PAD 2944       // 23*128

typedef __attribute__((ext_vector_type(8))) short short8;
typedef __attribute__((ext_vector_type(4))) float f32x4;

__device__ __forceinline__ unsigned short f2b(float x) {
  union { float f; unsigned u; } v; v.f = x;
  unsigned r = (v.u + 0x7FFFu + ((v.u >> 16) & 1u)) >> 16;
  return (unsigned short)r;
}

__device__ __forceinline__ void gload16(const void* g, void* l) {
  __builtin_amdgcn_global_load_lds(
      (const __attribute__((address_space(1))) void*)g,
      (__attribute__((address_space(3))) void*)l, 16, 0, 0);
}

// ---- cast x (fp32 -> bf16), vectorized ----
__global__ __launch_bounds__(256) void cast_x_kernel(const float* __restrict__ in,
                                                     unsigned short* __restrict__ out,
                                                     int n4) {
  int idx = blockIdx.x * 256 + threadIdx.x;
  if (idx >= n4) return;
  float4 v = ((const float4*)in)[idx];
  ushort4 o;
  o.x = f2b(v.x); o.y = f2b(v.y); o.z = f2b(v.z); o.w = f2b(v.w);
  ((ushort4*)out)[idx] = o;
}

// ---- transpose + cast (fp32 in): out[n*K + k] = (bf16) in[k*ldin + n] ----
__global__ __launch_bounds__(256) void transpose_cast(const float* __restrict__ in,
                                                      long ldin,
                                                      unsigned short* __restrict__ out,
                                                      int K, int N) {
  __shared__ float t[32][33];
  const int n0 = blockIdx.x * 32, k0 = blockIdx.y * 32;
  const int tx = threadIdx.x, ty = threadIdx.y;
#pragma unroll
  for (int i = 0; i < 4; ++i) {
    int k = k0 + ty + i * 8;
    int n = n0 + tx;
    t[ty + i * 8][tx] = (n < N) ? in[(long)k * ldin + n] : 0.f;
  }
  __syncthreads();
#pragma unroll
  for (int i = 0; i < 4; ++i) {
    int n = n0 + ty + i * 8;
    int k = k0 + tx;
    out[(long)n * K + k] = f2b(t[tx][ty + i * 8]);
  }
}

// ---- RoPE cos/sin table: [2048][32] each ----
__global__ __launch_bounds__(256) void rope_table(const int* __restrict__ pos,
                                                  float* __restrict__ ct,
                                                  float* __restrict__ st) {
  int tid = blockIdx.x * 256 + threadIdx.x;   // < 2048*32
  int t = tid >> 5, i = tid & 31;
  float p = (float)pos[t];
  float f = p * expf(-(float)i * (11.918390573078392f / 32.f));
  ct[tid] = cosf(f);
  st[tid] = sinf(f);
}

// ==== shared GEMM body macro: 128x128 tile, BK=64, 4 waves (2x2), m97 structure ====
// NXT = grid x-tiles (compile-time); includes bijective XCD swizzle (T1, m204).
#define GEMM128_BODY(Aptr, Bptr, lda, NXT)                                                \
  __shared__ char lA[128 * 128];                                                          \
  __shared__ char lB[128 * 128];                                                          \
  const int tid = threadIdx.x;                                                            \
  const int lane = tid & 63;                                                              \
  const int w = tid >> 6;                                                                 \
  const int m16 = lane & 15, g4 = lane >> 4;                                              \
  const int wr = w >> 1, wc = w & 1;                                                      \
  const int _nwg = (NXT) * gridDim.y;                                                     \
  const int _hw = blockIdx.y * (NXT) + blockIdx.x;                                        \
  const int _lg = (_hw & 7) * (_nwg >> 3) + (_hw >> 3);                                   \
  const int bm = (_lg / (NXT)) * 128, bn = (_lg % (NXT)) * 128;                           \
  const size_t strb = (size_t)(lda) * 2;                                                  \
  const int srow = tid >> 3;                                                              \
  const int scolb = ((tid & 7) * 16) ^ ((srow & 7) << 4);                                 \
  const int sdst = w * 1024;                                                              \
  const char* ga0 = (const char*)(Aptr) + (size_t)(bm + srow) * strb + scolb;             \
  const char* gb0 = (const char*)(Bptr) + (size_t)(bn + srow) * strb + scolb;             \
  const int swz = (m16 & 7) << 4;                                                         \
  const int kc0 = (g4 * 16) ^ swz;                                                        \
  const int kc1 = (64 + g4 * 16) ^ swz;                                                   \
  f32x4 acc[4][4];                                                                        \
  _Pragma("unroll") for (int i = 0; i < 4; ++i)                                           \
  _Pragma("unroll") for (int j = 0; j < 4; ++j) acc[i][j] = (f32x4){0.f, 0.f, 0.f, 0.f};  \
  const int NT = (lda) >> 6;                                                              \
  for (int t = 0; t < NT; ++t) {                                                          \
    const size_t ko = (size_t)t * 128;                                                    \
    __syncthreads();                                                                      \
    _Pragma("unroll") for (int i = 0; i < 4; ++i) {                                       \
      gload16(ga0 + (size_t)(i * 32) * strb + ko, lA + i * 4096 + sdst);                  \
      gload16(gb0 + (size_t)(i * 32) * strb + ko, lB + i * 4096 + sdst);                  \
    }                                                                                     \
    __syncthreads();                                                                      \
    short8 af[4][2], bf[4][2];                                                            \
    _Pragma("unroll") for (int mq = 0; mq < 4; ++mq) {                                    \
      const int row = wr * 64 + mq * 16 + m16;                                            \
      af[mq][0] = *(const short8*)(lA + row * 128 + kc0);                                 \
      af[mq][1] = *(const short8*)(lA + row * 128 + kc1);                                 \
    }                                                                                     \
    _Pragma("unroll") for (int nf = 0; nf < 4; ++nf) {                                    \
      const int row = wc * 64 + nf * 16 + m16;                                            \
      bf[nf][0] = *(const short8*)(lB + row * 128 + kc0);                                 \
      bf[nf][1] = *(const short8*)(lB + row * 128 + kc1);                                 \
    }                                                                                     \
    __builtin_amdgcn_s_setprio(1);                                                        \
    _Pragma("unroll") for (int mq = 0; mq < 4; ++mq)                                      \
    _Pragma("unroll") for (int nf = 0; nf < 4; ++nf) {                                    \
      acc[mq][nf] = __builtin_amdgcn_mfma_f32_16x16x32_bf16(af[mq][0], bf[nf][0], acc[mq][nf], 0, 0, 0); \
      acc[mq][nf] = __builtin_amdgcn_mfma_f32_16x16x32_bf16(af[mq][1], bf[nf][1], acc[mq][nf], 0, 0, 0); \
    }                                                                                     \
    __builtin_amdgcn_s_setprio(0);                                                        \
  }

// ---- plain GEMM (fp32 C out) -- wo projection (grid x = 23) ----
__global__ __launch_bounds__(256, 3) void gemm128(const unsigned short* __restrict__ A,
                                                  const unsigned short* __restrict__ Bt,
                                                  float* __restrict__ C,
                                                  int lda, int ldc, int Nvalid) {
  GEMM128_BODY(A, Bt, lda, 23)
#pragma unroll
  for (int mq = 0; mq < 4; ++mq) {
    const size_t row = bm + wr * 64 + mq * 16 + g4 * 4;
#pragma unroll
    for (int nf = 0; nf < 4; ++nf) {
      const int col = bn + wc * 64 + nf * 16 + m16;
      if (col < Nvalid) {
#pragma unroll
        for (int r = 0; r < 4; ++r)
          C[(row + r) * (size_t)ldc + col] = acc[mq][nf][r];
      }
    }
  }
}

// ---- QKV GEMM with fused RoPE + pack epilogue (grid x = 40) ----
__global__ __launch_bounds__(256, 3) void gemm128_qkv(const unsigned short* __restrict__ A,
                                                      const unsigned short* __restrict__ Bt,
                                                      const float* __restrict__ ct,
                                                      const float* __restrict__ st,
                                                      unsigned short* __restrict__ qb,
                                                      unsigned short* __restrict__ kb,
                                                      unsigned short* __restrict__ vtb,
                                                      int lda) {
  GEMM128_BODY(A, Bt, lda, 40)
  const int region = (bn < 4096) ? 0 : ((bn < 4608) ? 1 : 2);
#pragma unroll
  for (int mq = 0; mq < 4; ++mq) {
    const int row = bm + wr * 64 + mq * 16 + g4 * 4;   // token index base (+r)
    if (region == 2) {
#pragma unroll
      for (int nf = 0; nf < 4; ++nf) {
        const int d = (bn - 4608) + wc * 64 + nf * 16 + m16;
#pragma unroll
        for (int r = 0; r < 4; ++r) {
          const int t = row + r;
          const int b = t >> 10, sidx = t & 1023;
          vtb[((size_t)(b * NKVD + d)) * SS + sidx] = f2b(acc[mq][nf][r]);
        }
      }
    } else {
#pragma unroll
      for (int nf = 0; nf < 2; ++nf) {
        const int i = nf * 16 + m16;
#pragma unroll
        for (int r = 0; r < 4; ++r) {
          const int t = row + r;
          const int b = t >> 10, sidx = t & 1023;
          const float x1 = acc[mq][nf][r], x2 = acc[mq][nf + 2][r];
          const float c = ct[t * 32 + i], s = st[t * 32 + i];
          if (region == 0) {
            const int h = (bn >> 6) + wc;
            unsigned short* dst = qb + (((size_t)(b * NH + h)) * SS + sidx) * HD;
            dst[i]      = f2b((x1 * c - x2 * s) * 0.125f);
            dst[i + 32] = f2b((x1 * s + x2 * c) * 0.125f);
          } else {
            const int hk = ((bn - 4096) >> 6) + wc;
            unsigned short* dst = kb + (((size_t)(b * NKV + hk)) * SS + sidx) * HD;
            dst[i]      = f2b(x1 * c - x2 * s);
            dst[i + 32] = f2b(x1 * s + x2 * c);
          }
        }
      }
    }
  }
}

// ---- flash attention (R12-validated body; CU load-balance qblk remap) ----
// Grid = 512 blocks = exactly 2 residency slots x 256 CU. Dispatch round-robins
// across XCDs, so CU c hosts linear blocks {c, c+256}. Remap so that pair gets
// qblk summing to 3 (work nt=(qblk+1)*4 balanced: every CU does 20 tile-units)
// and the SAME bh (shared K/V stream -> L2 reuse).
__global__ __launch_bounds__(512) void attn_fwd(const unsigned short* __restrict__ qb,
                                                const unsigned short* __restrict__ kb,
                                                const unsigned short* __restrict__ vtb,
                                                unsigned short* __restrict__ ao) {
  __shared__ unsigned short kB[2][64 * 64];
  __shared__ unsigned short vB[2][64 * 64];
  __shared__ unsigned short pB[8][32 * 64];
  const int tid = threadIdx.x, lane = tid & 63, w = tid >> 6;
  const int lid = blockIdx.y * 4 + blockIdx.x;      // linear dispatch id, 0..511
  const int j = lid & 255, half = lid >> 8;
  const int qblk = half ? ((j & 1) ? 2 : 3) : ((j & 1) ? 1 : 0);
  const int bh = j >> 1;
  const int b = bh >> 6, h = bh & 63, hkv = h >> 3;
  const int m16 = lane & 15, g4 = lane >> 4;
  const int rbase = qblk * 256 + w * 32;

  const unsigned short* qp =
      qb + (((size_t)(b * NH + h)) * SS + rbase + m16) * HD + g4 * 8;
  const short8 q00 = *(const short8*)(qp);
  const short8 q01 = *(const short8*)(qp + 32);
  const short8 q10 = *(const short8*)(qp + 16 * HD);
  const short8 q11 = *(const short8*)(qp + 16 * HD + 32);

  const char* kbp = (const char*)(kb + ((size_t)(b * NKV + hkv)) * SS * HD);
  const char* vbp = (const char*)(vtb + ((size_t)(b * NKV + hkv)) * HD * SS);

  const int lrow = lane >> 3;
  const int lcolb = ((lane & 7) * 16) ^ ((lrow & 7) << 4);
  unsigned short* kDst0 = &kB[0][w * 512];
  unsigned short* kDst1 = &kB[1][w * 512];
  unsigned short* vDst0 = &vB[0][w * 512];
  unsigned short* vDst1 = &vB[1][w * 512];
  const size_t kRowOff = (size_t)(w * 8 + lrow) * 128 + lcolb;
  const size_t vRowOff = (size_t)(w * 8 + lrow) * 2048 + lcolb;

  const short8 ones = {(short)0x3F80, (short)0x3F80, (short)0x3F80, (short)0x3F80,
                       (short)0x3F80, (short)0x3F80, (short)0x3F80, (short)0x3F80};

  f32x4 o0[4], o1[4];
#pragma unroll
  for (int n = 0; n < 4; ++n) { o0[n] = (f32x4){0,0,0,0}; o1[n] = (f32x4){0,0,0,0}; }
  f32x4 lacc0 = (f32x4){0,0,0,0}, lacc1 = (f32x4){0,0,0,0};
  float mrow0[4] = {-1e30f,-1e30f,-1e30f,-1e30f};
  float mrow1[4] = {-1e30f,-1e30f,-1e30f,-1e30f};

  char* pw = (char*)pB[w];
  const int swz_m = (m16 & 7) << 4;
  const int nt = (qblk + 1) * 4;

  gload16(kbp + kRowOff, kDst0);
  gload16(vbp + vRowOff, vDst0);
  __syncthreads();

  for (int t = 0; t < nt; ++t) {
    const int k0 = t * 64;
    const char* kLds = (const char*)kB[t & 1];
    const char* vLds = (const char*)vB[t & 1];
    if (t + 1 < nt) {
      if (t & 1) { gload16(kbp + (size_t)(t + 1) * 8192 + kRowOff, kDst0);
                   gload16(vbp + (size_t)(t + 1) * 128  + vRowOff, vDst0); }
      else       { gload16(kbp + (size_t)(t + 1) * 8192 + kRowOff, kDst1);
                   gload16(vbp + (size_t)(t + 1) * 128  + vRowOff, vDst1); }
    }
    if (k0 < rbase + 32) {
      short8 kf0[4], kf1[4];
#pragma unroll
      for (int kf = 0; kf < 4; ++kf) {
        const int rb = (kf * 16 + m16) * 128;
        kf0[kf] = *(const short8*)(kLds + ((rb + g4 * 16) ^ swz_m));
        kf1[kf] = *(const short8*)(kLds + ((rb + 64 + g4 * 16) ^ swz_m));
      }
      f32x4 s0[4], s1[4];
      __builtin_amdgcn_s_setprio(1);
#pragma unroll
      for (int kf = 0; kf < 4; ++kf) {
        f32x4 z = (f32x4){0,0,0,0};
        z = __builtin_amdgcn_mfma_f32_16x16x32_bf16(q00, kf0[kf], z, 0, 0, 0);
        z = __builtin_amdgcn_mfma_f32_16x16x32_bf16(q01, kf1[kf], z, 0, 0, 0);
        s0[kf] = z;
        f32x4 z2 = (f32x4){0,0,0,0};
        z2 = __builtin_amdgcn_mfma_f32_16x16x32_bf16(q10, kf0[kf], z2, 0, 0, 0);
        z2 = __builtin_amdgcn_mfma_f32_16x16x32_bf16(q11, kf1[kf], z2, 0, 0, 0);
        s1[kf] = z2;
      }
      __builtin_amdgcn_s_setprio(0);
      if (k0 + 63 >= rbase) {
#pragma unroll
        for (int kf = 0; kf < 4; ++kf)
#pragma unroll
          for (int r = 0; r < 4; ++r) {
            const int col = k0 + kf * 16 + m16;
            if (col > rbase + g4 * 4 + r)      s0[kf][r] = -1e30f;
            if (col > rbase + 16 + g4 * 4 + r) s1[kf][r] = -1e30f;
          }
      }
      int grow = 0;
#pragma unroll
      for (int kf = 0; kf < 4; ++kf)
#pragma unroll
        for (int r = 0; r < 4; ++r) {
          grow |= (s0[kf][r] > mrow0[r] + 8.f);
          grow |= (s1[kf][r] > mrow1[r] + 8.f);
        }
      if (__any(grow)) {
        float mx0[4], mx1[4];
#pragma unroll
        for (int r = 0; r < 4; ++r) {
          mx0[r] = fmaxf(fmaxf(s0[0][r], s0[1][r]), fmaxf(s0[2][r], s0[3][r]));
          mx1[r] = fmaxf(fmaxf(s1[0][r], s1[1][r]), fmaxf(s1[2][r], s1[3][r]));
        }
#pragma unroll
        for (int off = 1; off <= 8; off <<= 1)
#pragma unroll
          for (int r = 0; r < 4; ++r) {
            mx0[r] = fmaxf(mx0[r], __shfl_xor(mx0[r], off));
            mx1[r] = fmaxf(mx1[r], __shfl_xor(mx1[r], off));
          }
#pragma unroll
        for (int r = 0; r < 4; ++r) {
          float mn0 = fmaxf(mrow0[r], mx0[r]);
          float sc0 = __expf(mrow0[r] - mn0);
          mrow0[r] = mn0; lacc0[r] *= sc0;
          float mn1 = fmaxf(mrow1[r], mx1[r]);
          float sc1 = __expf(mrow1[r] - mn1);
          mrow1[r] = mn1; lacc1[r] *= sc1;
#pragma unroll
          for (int n = 0; n < 4; ++n) { o0[n][r] *= sc0; o1[n][r] *= sc1; }
        }
      }
#pragma unroll
      for (int kf = 0; kf < 4; ++kf)
#pragma unroll
        for (int r = 0; r < 4; ++r) {
          const int colb = (kf * 16 + m16) * 2;
          int row = g4 * 4 + r;
          *(unsigned short*)(pw + ((row * 128 + colb) ^ ((row & 7) << 4))) =
              f2b(__expf(s0[kf][r] - mrow0[r]));
          row += 16;
          *(unsigned short*)(pw + ((row * 128 + colb) ^ ((row & 7) << 4))) =
              f2b(__expf(s1[kf][r] - mrow1[r]));
        }
      const int prb0 = m16 * 128, prb1 = (16 + m16) * 128;
      short8 pf00 = *(const short8*)(pw + ((prb0 + g4 * 16) ^ swz_m));
      short8 pf01 = *(const short8*)(pw + ((prb0 + 64 + g4 * 16) ^ swz_m));
      short8 pf10 = *(const short8*)(pw + ((prb1 + g4 * 16) ^ swz_m));
      short8 pf11 = *(const short8*)(pw + ((prb1 + 64 + g4 * 16) ^ swz_m));
      __builtin_amdgcn_s_setprio(1);
      lacc0 = __builtin_amdgcn_mfma_f32_16x16x32_bf16(pf00, ones, lacc0, 0, 0, 0);
      lacc0 = __builtin_amdgcn_mfma_f32_16x16x32_bf16(pf01, ones, lacc0, 0, 0, 0);
      lacc1 = __builtin_amdgcn_mfma_f32_16x16x32_bf16(pf10, ones, lacc1, 0, 0, 0);
      lacc1 = __builtin_amdgcn_mfma_f32_16x16x32_bf16(pf11, ones, lacc1, 0, 0, 0);
#pragma unroll
      for (int n = 0; n < 4; ++n) {
        const int rb = (n * 16 + m16) * 128;
        short8 vf0 = *(const short8*)(vLds + ((rb + g4 * 16) ^ swz_m));
        short8 vf1 = *(const short8*)(vLds + ((rb + 64 + g4 * 16) ^ swz_m));
        o0[n] = __builtin_amdgcn_mfma_f32_16x16x32_bf16(pf00, vf0, o0[n], 0, 0, 0);
        o0[n] = __builtin_amdgcn_mfma_f32_16x16x32_bf16(pf01, vf1, o0[n], 0, 0, 0);
        o1[n] = __builtin_amdgcn_mfma_f32_16x16x32_bf16(pf10, vf0, o1[n], 0, 0, 0);
        o1[n] = __builtin_amdgcn_mfma_f32_16x16x32_bf16(pf11, vf1, o1[n], 0, 0, 0);
      }
      __builtin_amdgcn_s_setprio(0);
    }
    __syncthreads();
  }

  float inv0[4], inv1[4];
#pragma unroll
  for (int r = 0; r < 4; ++r) { inv0[r] = 1.f / lacc0[r]; inv1[r] = 1.f / lacc1[r]; }
  const size_t row0 = (size_t)b * SS + rbase + g4 * 4;
#pragma unroll
  for (int n = 0; n < 4; ++n)
#pragma unroll
    for (int r = 0; r < 4; ++r) {
      ao[(row0 + r) * (size_t)NQ + h * 64 + n * 16 + m16] = f2b(o0[n][r] * inv0[r]);
      ao[(row0 + 16 + r) * (size_t)NQ + h * 64 + n * 16 + m16] = f2b(o1[n][r] * inv1[r]);
    }
}

// ---- workspace layout (bytes), total 103,677,952 ----
constexpr size_t OFF_XB    = 0;
constexpr size_t OFF_WQKVT = 11796480;
constexpr size_t OFF_WOT   = 41287680;
constexpr size_t OFF_COS   = 65404928;
constexpr size_t OFF_SIN   = 65667072;
constexpr size_t OFF_QB    = 65929216;
constexpr size_t OFF_KB    = 82706432;
constexpr size_t OFF_VTB   = 84803584;
constexpr size_t OFF_ATTNB = 86900736;

extern "C" void kernel_launch(void* const* d_in, const int* in_sizes, int n_in,
                              void* d_out, int out_size, void* d_ws, size_t ws_size,
                              hipStream_t stream) {
  const float* x  = (const float*)d_in[0];
  const float* wq = (const float*)d_in[1];
  const float* wk = (const float*)d_in[2];
  const float* wv = (const float*)d_in[3];
  const float* wo = (const float*)d_in[4];
  const int* pos  = (const int*)d_in[5];
  float* out = (float*)d_out;
  char* ws = (char*)d_ws;

  unsigned short* xb    = (unsigned short*)(ws + OFF_XB);
  unsigned short* wqkvt = (unsigned short*)(ws + OFF_WQKVT);
  unsigned short* wot   = (unsigned short*)(ws + OFF_WOT);
  float* ct             = (float*)(ws + OFF_COS);
  float* st             = (float*)(ws + OFF_SIN);
  unsigned short* qbuf  = (unsigned short*)(ws + OFF_QB);
  unsigned short* kbuf  = (unsigned short*)(ws + OFF_KB);
  unsigned short* vtb   = (unsigned short*)(ws + OFF_VTB);
  unsigned short* attnb = (unsigned short*)(ws + OFF_ATTNB);

  cast_x_kernel<<<(M_TOK * HIDDEN / 4 + 255) / 256, 256, 0, stream>>>(x, xb, M_TOK * HIDDEN / 4);
  rope_table<<<(M_TOK * 32) / 256, 256, 0, stream>>>(pos, ct, st);
  transpose_cast<<<dim3(NQ / 32, HIDDEN / 32), dim3(32, 8), 0, stream>>>(
      wq, NQ, wqkvt, HIDDEN, NQ);
  transpose_cast<<<dim3(NKVD / 32, HIDDEN / 32), dim3(32, 8), 0, stream>>>(
      wk, NKVD, wqkvt + (size_t)NQ * HIDDEN, HIDDEN, NKVD);
  transpose_cast<<<dim3(NKVD / 32, HIDDEN / 32), dim3(32, 8), 0, stream>>>(
      wv, NKVD, wqkvt + (size_t)(NQ + NKVD) * HIDDEN, HIDDEN, NKVD);
  transpose_cast<<<dim3(NOUT_PAD / 32, NQ / 32), dim3(32, 8), 0, stream>>>(
      wo, NOUT, wot, NQ, NOUT);
  // QKV projection with fused RoPE+pack epilogue: grid 40x16 = 640 blocks (XCD-swizzled)
  gemm128_qkv<<<dim3(NQKV / 128, M_TOK / 128), 256, 0, stream>>>(
      xb, wqkvt, ct, st, qbuf, kbuf, vtb, HIDDEN);
  // attention (qblk/bh remapped for CU load balance)
  attn_fwd<<<dim3(4, BB * NH), 512, 0, stream>>>(qbuf, kbuf, vtb, attnb);
  // output projection: grid 23x16 = 368 blocks (XCD-swizzled), fp32 direct to d_out
  gemm128<<<dim3(NOUT_PAD / 128, M_TOK / 128), 256, 0, stream>>>(
      attnb, wot, out, NQ, NOUT, NOUT);
}